// Round 4
// baseline (414.624 us; speedup 1.0000x reference)
//
#include <hip/hip_runtime.h>

#define EMBED 1024
#define HID   4096
#define NB    4
#define SEQ   2048

typedef __attribute__((ext_vector_type(8))) __bf16 bf16x8;
typedef __attribute__((ext_vector_type(4))) float  f32x4;
typedef __attribute__((ext_vector_type(4))) int    i32x4;
typedef unsigned short u16;

__device__ __forceinline__ u16 f2bf(float f) {
  unsigned u = __float_as_uint(f);
  u += 0x7FFFu + ((u >> 16) & 1u);
  return (u16)(u >> 16);
}

typedef const __attribute__((address_space(1))) unsigned int* gas_t;
typedef __attribute__((address_space(3))) unsigned int* las_t;
__device__ __forceinline__ void gld16(const void* g, void* l) {
  __builtin_amdgcn_global_load_lds((gas_t)g, (las_t)l, 16, 0, 0);
}

#define RD16(p)       __builtin_bit_cast(bf16x8, *(const i32x4*)(p))
#define MFMA16(a,b,c) __builtin_amdgcn_mfma_f32_16x16x32_bf16(a, b, c, 0, 0, 0)
#define SCHED0()      __builtin_amdgcn_sched_barrier(0)
#define BARR()        __builtin_amdgcn_s_barrier()
#define LGKM(n)       asm volatile("s_waitcnt lgkmcnt(" #n ")" ::: "memory")
#define VMW(n)        asm volatile("s_waitcnt vmcnt(" #n ")" ::: "memory")

// ---------------------------------------------------------------------------
// 256x256 NT GEMM, fragment-pipelined: C[m][n] = sum_k A[m][k]*B[n][k]
// BK=64, 512 thr (8 waves 2Mx4N, per-wave 128x64), 2 LDS buffers (128KB).
// Per K-tile: 4 phases x 16 MFMA. Fragments are PIPELINED: B(8)+A-pair0
// pre-issued at previous tile's ph3; each phase issues the NEXT pair's 4
// ds_reads, waits lgkmcnt(4) (current ready, next in flight under MFMA).
// Stage schedule + vmcnt(6) ledger identical to the round-3 proven one:
// after ph3's VMW(6)+BARR, the next tile's buffer is fully landed.
// EPI: 0 bias->bf16 | 1 *scale->f32 | 3 bias,relu->bf16 | 4 bias,+add->f32
// ---------------------------------------------------------------------------
template<int EPI>
__global__ __launch_bounds__(512, 2) void gemm256(
    const u16* __restrict__ A, int lda, long long astr,
    const u16* __restrict__ B, int ldb, long long bstr,
    void* __restrict__ C, int ldc, long long cstr,
    const float* __restrict__ bias,
    const float* __restrict__ add,
    float scale, int Kdim)
{
  __shared__ char lds[131072];   // buf b: A at b*65536, B at b*65536+32768

  const int tid  = threadIdx.x;
  const int lane = tid & 63;
  const int w    = tid >> 6;
  const int wr   = w >> 2, wc = w & 3;    // 2x4 waves -> 128x64 per wave
  const int l15  = lane & 15, l4 = lane >> 4;

  // T1: XCD swizzle
  const int gx   = gridDim.x;
  const int nwg  = gx * gridDim.y;
  const int orig = blockIdx.y * gx + blockIdx.x;
  const int t    = ((nwg & 7) == 0) ? ((orig & 7) * (nwg >> 3) + (orig >> 3)) : orig;
  const int bx   = t % gx, by = t / gx;

  const u16* Ab = A + (size_t)blockIdx.z * astr + (size_t)by * 256 * lda;
  const u16* Bb = B + (size_t)blockIdx.z * bstr + (size_t)bx * 256 * ldb;

  // staging: 8KB per issue (512 thr x 16B), linear LDS dest, pre-swizzled src
  const int    srow = tid >> 3;
  const size_t sa   = (size_t)srow * lda + (size_t)(((tid & 7) ^ (srow & 7)) * 8);
  const size_t sb   = (size_t)srow * ldb + (size_t)(((tid & 7) ^ (srow & 7)) * 8);
  const int    ldst = tid * 16;

  auto stA = [&](int buf, int q, int kk) {
    gld16(Ab + (size_t)(q * 64) * lda + kk + sa, lds + buf * 65536 + q * 8192 + ldst);
  };
  auto stB = [&](int buf, int i, int kk) {
    gld16(Bb + (size_t)(i * 64) * ldb + kk + sb, lds + buf * 65536 + 32768 + i * 8192 + ldst);
  };

  // LDS read offsets: row*128B, chunk XOR (row&7) swizzle (0-conflict, proven)
  const int arow = (wr * 128 + l15) * 128;
  const int brow = 32768 + (wc * 64 + l15) * 128;
  const int cp0  = ((0 + l4) ^ (l15 & 7)) * 16;
  const int cp1  = ((4 + l4) ^ (l15 & 7)) * 16;

  f32x4 acc[8][4] = {};
  bf16x8 b0, b1, b2, b3, b4, b5, b6, b7;       // tile-persistent B fragments
  bf16x8 p0, p1, p2, p3, q0, q1, q2, q3;       // ping-pong A pairs

#define AREAD(d0, d1, d2, d3, LB, MP) do { \
    d0 = RD16((LB) + arow + (MP) * 4096 + cp0); \
    d1 = RD16((LB) + arow + (MP) * 4096 + cp1); \
    d2 = RD16((LB) + arow + (MP) * 4096 + 2048 + cp0); \
    d3 = RD16((LB) + arow + (MP) * 4096 + 2048 + cp1); \
  } while (0)

#define BREAD(LB) do { \
    b0 = RD16((LB) + brow + 0 * 2048 + cp0); \
    b1 = RD16((LB) + brow + 1 * 2048 + cp0); \
    b2 = RD16((LB) + brow + 2 * 2048 + cp0); \
    b3 = RD16((LB) + brow + 3 * 2048 + cp0); \
    b4 = RD16((LB) + brow + 0 * 2048 + cp1); \
    b5 = RD16((LB) + brow + 1 * 2048 + cp1); \
    b6 = RD16((LB) + brow + 2 * 2048 + cp1); \
    b7 = RD16((LB) + brow + 3 * 2048 + cp1); \
  } while (0)

#define MBLK(MP, x0, x1, x2, x3) do { \
    __builtin_amdgcn_s_setprio(1); \
    acc[2*(MP)  ][0] = MFMA16(x0, b0, acc[2*(MP)  ][0]); \
    acc[2*(MP)  ][1] = MFMA16(x0, b1, acc[2*(MP)  ][1]); \
    acc[2*(MP)  ][2] = MFMA16(x0, b2, acc[2*(MP)  ][2]); \
    acc[2*(MP)  ][3] = MFMA16(x0, b3, acc[2*(MP)  ][3]); \
    acc[2*(MP)+1][0] = MFMA16(x2, b0, acc[2*(MP)+1][0]); \
    acc[2*(MP)+1][1] = MFMA16(x2, b1, acc[2*(MP)+1][1]); \
    acc[2*(MP)+1][2] = MFMA16(x2, b2, acc[2*(MP)+1][2]); \
    acc[2*(MP)+1][3] = MFMA16(x2, b3, acc[2*(MP)+1][3]); \
    acc[2*(MP)  ][0] = MFMA16(x1, b4, acc[2*(MP)  ][0]); \
    acc[2*(MP)  ][1] = MFMA16(x1, b5, acc[2*(MP)  ][1]); \
    acc[2*(MP)  ][2] = MFMA16(x1, b6, acc[2*(MP)  ][2]); \
    acc[2*(MP)  ][3] = MFMA16(x1, b7, acc[2*(MP)  ][3]); \
    acc[2*(MP)+1][0] = MFMA16(x3, b4, acc[2*(MP)+1][0]); \
    acc[2*(MP)+1][1] = MFMA16(x3, b5, acc[2*(MP)+1][1]); \
    acc[2*(MP)+1][2] = MFMA16(x3, b6, acc[2*(MP)+1][2]); \
    acc[2*(MP)+1][3] = MFMA16(x3, b7, acc[2*(MP)+1][3]); \
    __builtin_amdgcn_s_setprio(0); \
  } while (0)

  const int NT = Kdim >> 6;
  const int NI = NT >> 1;
  const char* L0 = lds;
  const char* L1 = lds + 65536;

  // prologue: tile0 -> buf0 (8 oldest), tile1 B + A q0,q2 -> buf1
  stB(0, 0, 0); stB(0, 1, 0); stB(0, 2, 0); stB(0, 3, 0);
  stA(0, 0, 0); stA(0, 1, 0); stA(0, 2, 0); stA(0, 3, 0);
  stB(1, 0, 64); stB(1, 1, 64); stB(1, 2, 64); stB(1, 3, 64);
  stA(1, 0, 64); stA(1, 2, 64);
  VMW(6);                        // retire 8 oldest = tile0 fully landed
  BARR(); SCHED0();
  AREAD(p0, p1, p2, p3, L0, 0);  // pre-issue tile0: A-pair0 + B (12 reads)
  BREAD(L0);

  for (int I = 0; I < NI; ++I) {
    const bool st = (I + 1 < NI);
    const int k1 = (2 * I + 1) * 64;
    const int k2 = (2 * I + 2) * 64;
    const int k3 = (2 * I + 3) * 64;

    // ================= K-tile 2I (buf0) =================
    // ph0: MFMA pair0 (p*), issue pair1 -> q*
    AREAD(q0, q1, q2, q3, L0, 1);
    stA(1, 1, k1); stA(1, 3, k1);
    LGKM(4); SCHED0();
    MBLK(0, p0, p1, p2, p3);
    SCHED0(); BARR();
    // ph1
    AREAD(p0, p1, p2, p3, L0, 2);
    if (st) { stB(0, 0, k2); stB(0, 1, k2); }
    LGKM(4); SCHED0();
    MBLK(1, q0, q1, q2, q3);
    SCHED0(); BARR();
    // ph2
    AREAD(q0, q1, q2, q3, L0, 3);
    if (st) { stB(0, 2, k2); stB(0, 3, k2); }
    LGKM(4); SCHED0();
    MBLK(2, p0, p1, p2, p3);
    SCHED0(); BARR();
    // ph3: drain stages for buf1, pre-issue tile 2I+1 fragments
    if (st) { stA(0, 0, k2); stA(0, 2, k2); VMW(6); }
    else    { VMW(0); }
    SCHED0(); BARR();
    AREAD(p0, p1, p2, p3, L1, 0);
    LGKM(4); SCHED0();
    MBLK(3, q0, q1, q2, q3);
    BREAD(L1);                    // overwrite b* AFTER last use (WAR-ordered)
    SCHED0(); BARR();

    // ================= K-tile 2I+1 (buf1) =================
    // ph0
    AREAD(q0, q1, q2, q3, L1, 1);
    if (st) { stA(0, 1, k2); stA(0, 3, k2); }
    LGKM(4); SCHED0();
    MBLK(0, p0, p1, p2, p3);
    SCHED0(); BARR();
    // ph1
    AREAD(p0, p1, p2, p3, L1, 2);
    if (st) { stB(1, 0, k3); stB(1, 1, k3); }
    LGKM(4); SCHED0();
    MBLK(1, q0, q1, q2, q3);
    SCHED0(); BARR();
    // ph2
    AREAD(q0, q1, q2, q3, L1, 3);
    if (st) { stB(1, 2, k3); stB(1, 3, k3); }
    LGKM(4); SCHED0();
    MBLK(2, p0, p1, p2, p3);
    SCHED0(); BARR();
    // ph3
    if (st) {
      stA(1, 0, k3); stA(1, 2, k3); VMW(6);
      SCHED0(); BARR();
      AREAD(p0, p1, p2, p3, L0, 0);
      LGKM(4); SCHED0();
      MBLK(3, q0, q1, q2, q3);
      BREAD(L0);
      SCHED0(); BARR();
    } else {
      LGKM(0); SCHED0();
      MBLK(3, q0, q1, q2, q3);
    }
  }
#undef AREAD
#undef BREAD
#undef MBLK

  // epilogue: C/D layout col=lane&15, row=(lane>>4)*4+reg (m89)
  const int bm0 = by * 256 + wr * 128;
  const int bn0 = bx * 256 + wc * 64;
  float* Cf = (float*)C;
  u16*   Ch = (u16*)C;
  #pragma unroll
  for (int mi = 0; mi < 8; ++mi) {
    #pragma unroll
    for (int ni = 0; ni < 4; ++ni) {
      const int col = bn0 + ni * 16 + l15;
      const int r0  = bm0 + mi * 16 + l4 * 4;
      float bv = 0.f;
      if (EPI == 0 || EPI == 3 || EPI == 4) bv = bias[col];
      #pragma unroll
      for (int r = 0; r < 4; ++r) {
        const size_t idx = (size_t)blockIdx.z * cstr + (size_t)(r0 + r) * ldc + col;
        const float v = acc[mi][ni][r];
        if      (EPI == 0) Ch[idx] = f2bf(v + bv);
        else if (EPI == 1) Cf[idx] = v * scale;
        else if (EPI == 3) Ch[idx] = f2bf(fmaxf(v + bv, 0.f));
        else if (EPI == 4) Cf[idx] = v + bv + add[idx];
      }
    }
  }
}

// ---------------------------------------------------------------------------
// Deep-pipelined 256x128 NT GEMM (round-2 proven) for narrow-N shapes
// ---------------------------------------------------------------------------
template<int EPI>
__global__ __launch_bounds__(512, 2) void gemm8p(
    const u16* __restrict__ A, int lda, long long astr,
    const u16* __restrict__ B, int ldb, long long bstr,
    void* __restrict__ C, int ldc, long long cstr,
    const float* __restrict__ bias,
    const float* __restrict__ add,
    float scale, int Kdim)
{
  __shared__ i32x4 lds4[9216];           // 3 slots x 48KB (A 32KB + B 16KB)
  const int SLOT = 49152;

  const int tid  = threadIdx.x;
  const int lane = tid & 63;
  const int w    = tid >> 6;
  const int wr   = w >> 1, wc = w & 1;
  const int l15  = lane & 15, l4 = lane >> 4;

  const int gx   = gridDim.x;
  const int nwg  = gx * gridDim.y;
  const int orig = blockIdx.y * gx + blockIdx.x;
  const int t    = ((nwg & 7) == 0) ? ((orig & 7) * (nwg >> 3) + (orig >> 3)) : orig;
  const int bx   = t % gx, by = t / gx;

  const u16* Ab = A + (size_t)blockIdx.z * astr + (size_t)by * 256 * lda;
  const u16* Bb = B + (size_t)blockIdx.z * bstr + (size_t)bx * 128 * ldb;

  size_t gaoff[4], gboff[2];
  #pragma unroll
  for (int i = 0; i < 4; ++i) {
    const int idx = i * 512 + tid, row = idx >> 3, gc = (idx & 7) ^ (row & 7);
    gaoff[i] = (size_t)row * lda + gc * 8;
  }
  #pragma unroll
  for (int j = 0; j < 2; ++j) {
    const int idx = j * 512 + tid, row = idx >> 3, gc = (idx & 7) ^ (row & 7);
    gboff[j] = (size_t)row * ldb + gc * 8;
  }

  int aoff[4], boff[4], cp16[2];
  #pragma unroll
  for (int m = 0; m < 4; ++m) aoff[m] = (wr * 64 + m * 16 + l15) * 128;
  #pragma unroll
  for (int n = 0; n < 4; ++n) boff[n] = 32768 + (wc * 64 + n * 16 + l15) * 128;
  cp16[0] = ((0 + l4) ^ (l15 & 7)) * 16;
  cp16[1] = ((4 + l4) ^ (l15 & 7)) * 16;

  f32x4 acc[4][4] = {};
  const int NT = Kdim >> 6;
  char* lbase = (char*)lds4;

  {
    char* s0 = lbase;
    char* s1 = lbase + SLOT;
    #pragma unroll
    for (int i = 0; i < 4; ++i) gld16(Ab + gaoff[i],      s0 + (i * 512 + w * 64) * 16);
    #pragma unroll
    for (int j = 0; j < 2; ++j) gld16(Bb + gboff[j],      s0 + 32768 + (j * 512 + w * 64) * 16);
    #pragma unroll
    for (int i = 0; i < 4; ++i) gld16(Ab + gaoff[i] + 64, s1 + (i * 512 + w * 64) * 16);
    #pragma unroll
    for (int j = 0; j < 2; ++j) gld16(Bb + gboff[j] + 64, s1 + 32768 + (j * 512 + w * 64) * 16);
  }

  int s = 0;
  for (int T = 0; T < NT; ++T) {
    const bool st  = (T + 2 < NT);
    const size_t kk = (size_t)(T + 2) * 64;
    const char* rA = lbase + s * SLOT;
    char* wS = lbase + ((s + 2 >= 3) ? (s - 1) : (s + 2)) * SLOT;

    if (T == NT - 1) VMW(0);
    else             VMW(6);
    BARR();
    SCHED0();

    bf16x8 b0, b1, b2, b3, a0, a1;

    b0 = RD16(rA + boff[0] + cp16[0]);
    b1 = RD16(rA + boff[1] + cp16[0]);
    b2 = RD16(rA + boff[2] + cp16[0]);
    b3 = RD16(rA + boff[3] + cp16[0]);
    a0 = RD16(rA + aoff[0] + cp16[0]);
    a1 = RD16(rA + aoff[1] + cp16[0]);
    if (st) {
      gld16(Ab + gaoff[0] + kk, wS + (0 * 512 + w * 64) * 16);
      gld16(Ab + gaoff[1] + kk, wS + (1 * 512 + w * 64) * 16);
    }
    BARR();
    LGKM(0);
    SCHED0();
    __builtin_amdgcn_s_setprio(1);
    acc[0][0] = MFMA16(a0, b0, acc[0][0]);
    acc[0][1] = MFMA16(a0, b1, acc[0][1]);
    acc[0][2] = MFMA16(a0, b2, acc[0][2]);
    acc[0][3] = MFMA16(a0, b3, acc[0][3]);
    acc[1][0] = MFMA16(a1, b0, acc[1][0]);
    acc[1][1] = MFMA16(a1, b1, acc[1][1]);
    acc[1][2] = MFMA16(a1, b2, acc[1][2]);
    acc[1][3] = MFMA16(a1, b3, acc[1][3]);
    __builtin_amdgcn_s_setprio(0);

    a0 = RD16(rA + aoff[2] + cp16[0]);
    a1 = RD16(rA + aoff[3] + cp16[0]);
    if (st) {
      gld16(Ab + gaoff[2] + kk, wS + (2 * 512 + w * 64) * 16);
      gld16(Ab + gaoff[3] + kk, wS + (3 * 512 + w * 64) * 16);
    }
    BARR();
    LGKM(0);
    SCHED0();
    __builtin_amdgcn_s_setprio(1);
    acc[2][0] = MFMA16(a0, b0, acc[2][0]);
    acc[2][1] = MFMA16(a0, b1, acc[2][1]);
    acc[2][2] = MFMA16(a0, b2, acc[2][2]);
    acc[2][3] = MFMA16(a0, b3, acc[2][3]);
    acc[3][0] = MFMA16(a1, b0, acc[3][0]);
    acc[3][1] = MFMA16(a1, b1, acc[3][1]);
    acc[3][2] = MFMA16(a1, b2, acc[3][2]);
    acc[3][3] = MFMA16(a1, b3, acc[3][3]);
    __builtin_amdgcn_s_setprio(0);

    b0 = RD16(rA + boff[0] + cp16[1]);
    b1 = RD16(rA + boff[1] + cp16[1]);
    b2 = RD16(rA + boff[2] + cp16[1]);
    b3 = RD16(rA + boff[3] + cp16[1]);
    a0 = RD16(rA + aoff[0] + cp16[1]);
    a1 = RD16(rA + aoff[1] + cp16[1]);
    if (st) {
      gld16(Bb + gboff[0] + kk, wS + 32768 + (0 * 512 + w * 64) * 16);
    }
    BARR();
    LGKM(0);
    SCHED0();
    __builtin_amdgcn_s_setprio(1);
    acc[0][0] = MFMA16(a0, b0, acc[0][0]);
    acc[0][1] = MFMA16(a0, b1, acc[0][1]);
    acc[0][2] = MFMA16(a0, b2, acc[0][2]);
    acc[0][3] = MFMA16(a0, b3, acc[0][3]);
    acc[1][0] = MFMA16(a1, b0, acc[1][0]);
    acc[1][1] = MFMA16(a1, b1, acc[1][1]);
    acc[1][2] = MFMA16(a1, b2, acc[1][2]);
    acc[1][3] = MFMA16(a1, b3, acc[1][3]);
    __builtin_amdgcn_s_setprio(0);

    a0 = RD16(rA + aoff[2] + cp16[1]);
    a1 = RD16(rA + aoff[3] + cp16[1]);
    if (st) {
      gld16(Bb + gboff[1] + kk, wS + 32768 + (1 * 512 + w * 64) * 16);
    }
    BARR();
    LGKM(0);
    SCHED0();
    __builtin_amdgcn_s_setprio(1);
    acc[2][0] = MFMA16(a0, b0, acc[2][0]);
    acc[2][1] = MFMA16(a0, b1, acc[2][1]);
    acc[2][2] = MFMA16(a0, b2, acc[2][2]);
    acc[2][3] = MFMA16(a0, b3, acc[2][3]);
    acc[3][0] = MFMA16(a1, b0, acc[3][0]);
    acc[3][1] = MFMA16(a1, b1, acc[3][1]);
    acc[3][2] = MFMA16(a1, b2, acc[3][2]);
    acc[3][3] = MFMA16(a1, b3, acc[3][3]);
    __builtin_amdgcn_s_setprio(0);

    s = (s + 1 == 3) ? 0 : s + 1;
  }

  const int bm0 = by * 256 + wr * 64;
  const int bn0 = bx * 128 + wc * 64;
  float* Cf = (float*)C;
  u16*   Ch = (u16*)C;
  #pragma unroll
  for (int mi = 0; mi < 4; ++mi) {
    #pragma unroll
    for (int ni = 0; ni < 4; ++ni) {
      const int col = bn0 + ni * 16 + l15;
      const int r0  = bm0 + mi * 16 + l4 * 4;
      float bv = 0.f;
      if (EPI == 0 || EPI == 3 || EPI == 4) bv = bias[col];
      #pragma unroll
      for (int r = 0; r < 4; ++r) {
        const size_t idx = (size_t)blockIdx.z * cstr + (size_t)(r0 + r) * ldc + col;
        const float v = acc[mi][ni][r];
        if      (EPI == 0) Ch[idx] = f2bf(v + bv);
        else if (EPI == 1) Cf[idx] = v * scale;
        else if (EPI == 2) Cf[idx] = v + add[idx];
        else if (EPI == 3) Ch[idx] = f2bf(fmaxf(v + bv, 0.f));
        else               Cf[idx] = v + bv + add[idx];
      }
    }
  }
}

// ---------------------------------------------------------------------------
__global__ __launch_bounds__(256) void ln_kernel(
    const float* __restrict__ x, const float* __restrict__ g,
    const float* __restrict__ be, u16* __restrict__ out)
{
  const int row = blockIdx.x;
  const int tid = threadIdx.x;
  const float4 v = ((const float4*)(x + (size_t)row * EMBED))[tid];
  float s  = v.x + v.y + v.z + v.w;
  float s2 = v.x * v.x + v.y * v.y + v.z * v.z + v.w * v.w;
  #pragma unroll
  for (int m = 1; m < 64; m <<= 1) { s += __shfl_xor(s, m); s2 += __shfl_xor(s2, m); }
  __shared__ float ls[4], ls2[4];
  const int w = tid >> 6;
  if ((tid & 63) == 0) { ls[w] = s; ls2[w] = s2; }
  __syncthreads();
  s  = ls[0] + ls[1] + ls[2] + ls[3];
  s2 = ls2[0] + ls2[1] + ls2[2] + ls2[3];
  const float mu   = s * (1.f / EMBED);
  const float var  = s2 * (1.f / EMBED) - mu * mu;
  const float rstd = rsqrtf(var + 1e-5f);
  const float4 gv = ((const float4*)g)[tid];
  const float4 bv = ((const float4*)be)[tid];
  ushort4 o;
  o.x = f2bf((v.x - mu) * rstd * gv.x + bv.x);
  o.y = f2bf((v.y - mu) * rstd * gv.y + bv.y);
  o.z = f2bf((v.z - mu) * rstd * gv.z + bv.z);
  o.w = f2bf((v.w - mu) * rstd * gv.w + bv.w);
  ((ushort4*)(out + (size_t)row * EMBED))[tid] = o;
}

// ---------------------------------------------------------------------------
__global__ __launch_bounds__(256) void softmax_kernel(
    const float* __restrict__ S, u16* __restrict__ P)
{
  const int tid = threadIdx.x;
  const size_t base = ((size_t)blockIdx.y * SEQ + blockIdx.x) * SEQ;
  const float4* src = (const float4*)(S + base);
  float4 a = src[tid];
  float4 b = src[tid + 256];
  float m = fmaxf(fmaxf(fmaxf(a.x, a.y), fmaxf(a.z, a.w)),
                  fmaxf(fmaxf(b.x, b.y), fmaxf(b.z, b.w)));
  #pragma unroll
  for (int msk = 1; msk < 64; msk <<= 1) m = fmaxf(m, __shfl_xor(m, msk));
  __shared__ float red[8];
  const int w = tid >> 6;
  if ((tid & 63) == 0) red[w] = m;
  __syncthreads();
  m = fmaxf(fmaxf(red[0], red[1]), fmaxf(red[2], red[3]));
  a.x = __expf(a.x - m); a.y = __expf(a.y - m); a.z = __expf(a.z - m); a.w = __expf(a.w - m);
  b.x = __expf(b.x - m); b.y = __expf(b.y - m); b.z = __expf(b.z - m); b.w = __expf(b.w - m);
  float s = a.x + a.y + a.z + a.w + b.x + b.y + b.z + b.w;
  #pragma unroll
  for (int msk = 1; msk < 64; msk <<= 1) s += __shfl_xor(s, msk);
  if ((tid & 63) == 0) red[4 + w] = s;
  __syncthreads();
  s = red[4] + red[5] + red[6] + red[7];
  const float inv = 1.0f / s;
  ushort4 oa, ob;
  oa.x = f2bf(a.x * inv); oa.y = f2bf(a.y * inv); oa.z = f2bf(a.z * inv); oa.w = f2bf(a.w * inv);
  ob.x = f2bf(b.x * inv); ob.y = f2bf(b.y * inv); ob.z = f2bf(b.z * inv); ob.w = f2bf(b.w * inv);
  ushort4* dst = (ushort4*)(P + base);
  dst[tid]       = oa;
  dst[tid + 256] = ob;
}

// ---------------------------------------------------------------------------
__global__ void transpose_cast_f32(const float* __restrict__ W, u16* __restrict__ Wt,
                                   int K, int N)
{
  __shared__ float t[32][33];
  const int tx = threadIdx.x, ty = threadIdx.y;
  const int n0 = blockIdx.x * 32, k0 = blockIdx.y * 32;
  #pragma unroll
  for (int i = 0; i < 4; ++i)
    t[ty + i * 8][tx] = W[(size_t)(k0 + ty + i * 8) * N + n0 + tx];
  __syncthreads();
  #pragma unroll
  for (int i = 0; i < 4; ++i)
    Wt[(size_t)(n0 + ty + i * 8) * K + k0 + tx] = f2bf(t[tx][ty + i * 8]);
}

__global__ void transpose_bf16(const u16* __restrict__ V, u16* __restrict__ Vt,
                               int sld, long long sstr, long long dstr)
{
  __shared__ u16 t[32][33];
  const int tx = threadIdx.x, ty = threadIdx.y;
  const int d0 = blockIdx.x * 32, s0 = blockIdx.y * 32;
  const size_t so = (size_t)blockIdx.z * sstr;
  const size_t do_ = (size_t)blockIdx.z * dstr;
  #pragma unroll
  for (int i = 0; i < 4; ++i)
    t[ty + i * 8][tx] = V[so + (size_t)(s0 + ty + i * 8) * sld + d0 + tx];
  __syncthreads();
  #pragma unroll
  for (int i = 0; i < 4; ++i)
    Vt[do_ + (size_t)(d0 + ty + i * 8) * SEQ + s0 + tx] = t[tx][ty + i * 8];
}

__global__ void concat_bias(const float* __restrict__ a, const float* __restrict__ b,
                            const float* __restrict__ c, float* __restrict__ o)
{
  const int i = blockIdx.x * 1024 + threadIdx.x;
  o[i] = (i < 1024) ? a[i] : (i < 2048) ? b[i - 1024] : c[i - 2048];
}

// ---------------------------------------------------------------------------
extern "C" void kernel_launch(void* const* d_in, const int* in_sizes, int n_in,
                              void* d_out, int out_size, void* d_ws, size_t ws_size,
                              hipStream_t stream)
{
  const float* x   = (const float*)d_in[0];
  const float* Wq  = (const float*)d_in[1];
  const float* bq  = (const float*)d_in[2];
  const float* Wk  = (const float*)d_in[3];
  const float* bk  = (const float*)d_in[4];
  const float* Wv  = (const float*)d_in[5];
  const float* bv  = (const float*)d_in[6];
  const float* W1  = (const float*)d_in[7];
  const float* b1  = (const float*)d_in[8];
  const float* W2  = (const float*)d_in[9];
  const float* b2  = (const float*)d_in[10];
  const float* g1  = (const float*)d_in[11];
  const float* be1 = (const float*)d_in[12];
  const float* g2  = (const float*)d_in[13];
  const float* be2 = (const float*)d_in[14];
  float* out = (float*)d_out;

  const size_t RD = (size_t)NB * SEQ * EMBED;

  char* base = (char*)d_ws;
  size_t o = 0;
  auto alloc = [&](size_t bytes) -> void* {
    o = (o + 255) & ~(size_t)255;
    void* p = base + o;
    o += bytes;
    return p;
  };

  u16*   wqkvT = (u16*)alloc((size_t)3 * EMBED * EMBED * 2);
  u16*   w1T   = (u16*)alloc((size_t)HID * EMBED * 2);
  u16*   w2T   = (u16*)alloc((size_t)EMBED * HID * 2);
  float* bqkv  = (float*)alloc(3072 * 4);
  u16*   h     = (u16*)alloc(RD * 2);
  u16*   QKV   = (u16*)alloc(RD * 3 * 2);
  u16*   Vt    = (u16*)alloc(RD * 2);
  float* x2    = (float*)alloc(RD * 4);

  const size_t need_batched = o + (size_t)NB * SEQ * SEQ * 6 + 1024;
  const int NZ = (ws_size >= need_batched) ? NB : 1;
  float* Sbuf = (float*)alloc((size_t)NZ * SEQ * SEQ * 4);
  u16*   Pb   = (u16*)alloc((size_t)NZ * SEQ * SEQ * 2);
  u16*   ff   = (NZ == NB) ? (u16*)Sbuf
                           : (u16*)alloc((size_t)NB * SEQ * HID * 2);

  const dim3 blk(512);
  const dim3 tblk(32, 8);

  transpose_cast_f32<<<dim3(32, 32), tblk, 0, stream>>>(Wq, wqkvT, EMBED, EMBED);
  transpose_cast_f32<<<dim3(32, 32), tblk, 0, stream>>>(Wk, wqkvT + (size_t)EMBED * EMBED, EMBED, EMBED);
  transpose_cast_f32<<<dim3(32, 32), tblk, 0, stream>>>(Wv, wqkvT + (size_t)2 * EMBED * EMBED, EMBED, EMBED);
  transpose_cast_f32<<<dim3(HID / 32, EMBED / 32), tblk, 0, stream>>>(W1, w1T, EMBED, HID);
  transpose_cast_f32<<<dim3(EMBED / 32, HID / 32), tblk, 0, stream>>>(W2, w2T, HID, EMBED);
  concat_bias<<<dim3(3), dim3(1024), 0, stream>>>(bq, bk, bv, bqkv);

  ln_kernel<<<dim3(NB * SEQ), dim3(256), 0, stream>>>(x, g1, be1, h);

  // fused QKV projection: [8192][3072], 256x256 tiles
  gemm256<0><<<dim3(3072 / 256, NB * SEQ / 256, 1), blk, 0, stream>>>(
      h, EMBED, 0LL, wqkvT, EMBED, 0LL, QKV, 3072, 0LL, bqkv, nullptr, 1.f, EMBED);

  transpose_bf16<<<dim3(EMBED / 32, SEQ / 32, NB), tblk, 0, stream>>>(
      QKV + 2048, Vt, 3072, (long long)SEQ * 3072, (long long)EMBED * SEQ);

  for (int b = 0; b < NB; b += NZ) {
    const u16* Qp  = QKV + (size_t)b * SEQ * 3072;
    const u16* Kp  = Qp + 1024;
    const u16* Vtp = Vt + (size_t)b * EMBED * SEQ;
    float* x2p     = x2 + (size_t)b * SEQ * EMBED;
    const float* xp = x + (size_t)b * SEQ * EMBED;
    gemm256<1><<<dim3(SEQ / 256, SEQ / 256, NZ), blk, 0, stream>>>(
        Qp, 3072, (long long)SEQ * 3072, Kp, 3072, (long long)SEQ * 3072,
        Sbuf, SEQ, (long long)SEQ * SEQ, nullptr, nullptr, 0.03125f, EMBED);
    softmax_kernel<<<dim3(SEQ, NZ), dim3(256), 0, stream>>>(Sbuf, Pb);
    gemm8p<2><<<dim3(EMBED / 128, SEQ / 256, NZ), blk, 0, stream>>>(
        Pb, SEQ, (long long)SEQ * SEQ, Vtp, SEQ, (long long)EMBED * SEQ,
        x2p, EMBED, (long long)SEQ * EMBED, nullptr, xp, 1.f, SEQ);
  }

  ln_kernel<<<dim3(NB * SEQ), dim3(256), 0, stream>>>(x2, g2, be2, h);

  gemm256<3><<<dim3(HID / 256, NB * SEQ / 256, 1), blk, 0, stream>>>(
      h, EMBED, 0LL, w1T, EMBED, 0LL, ff, HID, 0LL, b1, nullptr, 1.f, EMBED);
  gemm8p<4><<<dim3(EMBED / 128, NB * SEQ / 256, 1), blk, 0, stream>>>(
      ff, HID, 0LL, w2T, HID, 0LL, out, EMBED, 0LL, b2, x2, 1.f, HID);
}

// Round 5
// 341.624 us; speedup vs baseline: 1.2137x; 1.2137x over previous
//
#include <hip/hip_runtime.h>

#define EMBED 1024
#define HID   4096
#define NB    4
#define SEQ   2048

typedef __attribute__((ext_vector_type(8))) __bf16 bf16x8;
typedef __attribute__((ext_vector_type(4))) float  f32x4;
typedef __attribute__((ext_vector_type(4))) int    i32x4;
typedef unsigned short u16;

__device__ __forceinline__ u16 f2bf(float f) {
  unsigned u = __float_as_uint(f);
  u += 0x7FFFu + ((u >> 16) & 1u);
  return (u16)(u >> 16);
}

typedef const __attribute__((address_space(1))) unsigned int* gas_t;
typedef __attribute__((address_space(3))) unsigned int* las_t;
__device__ __forceinline__ void gld16(const void* g, void* l) {
  __builtin_amdgcn_global_load_lds((gas_t)g, (las_t)l, 16, 0, 0);
}

#define RD16(p)       __builtin_bit_cast(bf16x8, *(const i32x4*)(p))
#define MFMA16(a,b,c) __builtin_amdgcn_mfma_f32_16x16x32_bf16(a, b, c, 0, 0, 0)
#define SCHED0()      __builtin_amdgcn_sched_barrier(0)
#define BARR()        __builtin_amdgcn_s_barrier()
#define LGKM(n)       asm volatile("s_waitcnt lgkmcnt(" #n ")" ::: "memory")
#define VMW(n)        asm volatile("s_waitcnt vmcnt(" #n ")" ::: "memory")

// ---------------------------------------------------------------------------
// 256x256 NT GEMM (round-3 proven schedule, used for MLP1 only).
// BK=64, 512 thr (8 waves 2Mx4N, per-wave 128x64), 2 LDS buffers (128KB),
// 4 phases/K-tile x 16 MFMA, region-recycled staging, vmcnt(6) ledger.
// ---------------------------------------------------------------------------
template<int EPI>
__global__ __launch_bounds__(512, 2) void gemm256(
    const u16* __restrict__ A, int lda, long long astr,
    const u16* __restrict__ B, int ldb, long long bstr,
    void* __restrict__ C, int ldc, long long cstr,
    const float* __restrict__ bias,
    const float* __restrict__ add,
    float scale, int Kdim)
{
  __shared__ char lds[131072];   // buf b: A at b*65536, B at b*65536+32768

  const int tid  = threadIdx.x;
  const int lane = tid & 63;
  const int w    = tid >> 6;
  const int wr   = w >> 2, wc = w & 3;    // 2x4 waves -> 128x64 per wave
  const int l15  = lane & 15, l4 = lane >> 4;

  const int gx   = gridDim.x;
  const int nwg  = gx * gridDim.y;
  const int orig = blockIdx.y * gx + blockIdx.x;
  const int t    = ((nwg & 7) == 0) ? ((orig & 7) * (nwg >> 3) + (orig >> 3)) : orig;
  const int bx   = t % gx, by = t / gx;

  const u16* Ab = A + (size_t)blockIdx.z * astr + (size_t)by * 256 * lda;
  const u16* Bb = B + (size_t)blockIdx.z * bstr + (size_t)bx * 256 * ldb;

  const int    srow = tid >> 3;
  const size_t sa   = (size_t)srow * lda + (size_t)(((tid & 7) ^ (srow & 7)) * 8);
  const size_t sb   = (size_t)srow * ldb + (size_t)(((tid & 7) ^ (srow & 7)) * 8);
  const int    ldst = tid * 16;

  auto stA = [&](int buf, int q, int kk) {
    gld16(Ab + (size_t)(q * 64) * lda + kk + sa, lds + buf * 65536 + q * 8192 + ldst);
  };
  auto stB = [&](int buf, int i, int kk) {
    gld16(Bb + (size_t)(i * 64) * ldb + kk + sb, lds + buf * 65536 + 32768 + i * 8192 + ldst);
  };

  const int arow = (wr * 128 + l15) * 128;
  const int brow = 32768 + (wc * 64 + l15) * 128;
  const int cp0  = ((0 + l4) ^ (l15 & 7)) * 16;
  const int cp1  = ((4 + l4) ^ (l15 & 7)) * 16;

  f32x4 acc[8][4] = {};
  bf16x8 a0, a1, a2, a3, b0, b1, b2, b3, b4, b5, b6, b7;

  const int NT = Kdim >> 6;
  const int NI = NT >> 1;

#define BLOADS(LB) \
    b0 = RD16((LB) + brow + 0 * 2048 + cp0); \
    b1 = RD16((LB) + brow + 1 * 2048 + cp0); \
    b2 = RD16((LB) + brow + 2 * 2048 + cp0); \
    b3 = RD16((LB) + brow + 3 * 2048 + cp0); \
    b4 = RD16((LB) + brow + 0 * 2048 + cp1); \
    b5 = RD16((LB) + brow + 1 * 2048 + cp1); \
    b6 = RD16((LB) + brow + 2 * 2048 + cp1); \
    b7 = RD16((LB) + brow + 3 * 2048 + cp1);

#define PHASE(LB, MP, PRE, STG, VMST) do { \
    a0 = RD16((LB) + arow + (MP) * 4096 + cp0); \
    a1 = RD16((LB) + arow + (MP) * 4096 + cp1); \
    a2 = RD16((LB) + arow + (MP) * 4096 + 2048 + cp0); \
    a3 = RD16((LB) + arow + (MP) * 4096 + 2048 + cp1); \
    PRE STG VMST \
    SCHED0(); BARR(); LGKM(0); SCHED0(); \
    __builtin_amdgcn_s_setprio(1); \
    acc[2*(MP)  ][0] = MFMA16(a0, b0, acc[2*(MP)  ][0]); \
    acc[2*(MP)  ][1] = MFMA16(a0, b1, acc[2*(MP)  ][1]); \
    acc[2*(MP)  ][2] = MFMA16(a0, b2, acc[2*(MP)  ][2]); \
    acc[2*(MP)  ][3] = MFMA16(a0, b3, acc[2*(MP)  ][3]); \
    acc[2*(MP)+1][0] = MFMA16(a2, b0, acc[2*(MP)+1][0]); \
    acc[2*(MP)+1][1] = MFMA16(a2, b1, acc[2*(MP)+1][1]); \
    acc[2*(MP)+1][2] = MFMA16(a2, b2, acc[2*(MP)+1][2]); \
    acc[2*(MP)+1][3] = MFMA16(a2, b3, acc[2*(MP)+1][3]); \
    acc[2*(MP)  ][0] = MFMA16(a1, b4, acc[2*(MP)  ][0]); \
    acc[2*(MP)  ][1] = MFMA16(a1, b5, acc[2*(MP)  ][1]); \
    acc[2*(MP)  ][2] = MFMA16(a1, b6, acc[2*(MP)  ][2]); \
    acc[2*(MP)  ][3] = MFMA16(a1, b7, acc[2*(MP)  ][3]); \
    acc[2*(MP)+1][0] = MFMA16(a3, b4, acc[2*(MP)+1][0]); \
    acc[2*(MP)+1][1] = MFMA16(a3, b5, acc[2*(MP)+1][1]); \
    acc[2*(MP)+1][2] = MFMA16(a3, b6, acc[2*(MP)+1][2]); \
    acc[2*(MP)+1][3] = MFMA16(a3, b7, acc[2*(MP)+1][3]); \
    __builtin_amdgcn_s_setprio(0); \
    SCHED0(); BARR(); SCHED0(); \
  } while (0)

  // prologue: tile0 -> buf0 (8 oldest issues), tile1 B + A q0,q2 -> buf1
  stB(0, 0, 0); stB(0, 1, 0); stB(0, 2, 0); stB(0, 3, 0);
  stA(0, 0, 0); stA(0, 1, 0); stA(0, 2, 0); stA(0, 3, 0);
  stB(1, 0, 64); stB(1, 1, 64); stB(1, 2, 64); stB(1, 3, 64);
  stA(1, 0, 64); stA(1, 2, 64);
  VMW(6);
  BARR(); SCHED0();

  const char* L0 = lds;
  const char* L1 = lds + 65536;

  for (int I = 0; I < NI; ++I) {
    const bool st = (I + 1 < NI);
    const int k1 = (2 * I + 1) * 64;
    const int k2 = (2 * I + 2) * 64;
    const int k3 = (2 * I + 3) * 64;

    PHASE(L0, 0, BLOADS(L0), { stA(1, 1, k1); stA(1, 3, k1); }, ;);
    PHASE(L0, 1, ;, if (st) { stB(0, 0, k2); stB(0, 1, k2); }, ;);
    PHASE(L0, 2, ;, if (st) { stB(0, 2, k2); stB(0, 3, k2); }, ;);
    if (st) { PHASE(L0, 3, ;, { stA(0, 0, k2); stA(0, 2, k2); }, VMW(6);); }
    else    { PHASE(L0, 3, ;, ;, VMW(0);); }
    PHASE(L1, 0, BLOADS(L1), if (st) { stA(0, 1, k2); stA(0, 3, k2); }, ;);
    PHASE(L1, 1, ;, if (st) { stB(1, 0, k3); stB(1, 1, k3); }, ;);
    PHASE(L1, 2, ;, if (st) { stB(1, 2, k3); stB(1, 3, k3); }, ;);
    if (st) { PHASE(L1, 3, ;, { stA(1, 0, k3); stA(1, 2, k3); }, VMW(6);); }
    else    { PHASE(L1, 3, ;, ;, ;); }
  }
#undef PHASE
#undef BLOADS

  const int bm0 = by * 256 + wr * 128;
  const int bn0 = bx * 256 + wc * 64;
  float* Cf = (float*)C;
  u16*   Ch = (u16*)C;
  #pragma unroll
  for (int mi = 0; mi < 8; ++mi) {
    #pragma unroll
    for (int ni = 0; ni < 4; ++ni) {
      const int col = bn0 + ni * 16 + l15;
      const int r0  = bm0 + mi * 16 + l4 * 4;
      float bv = 0.f;
      if (EPI == 0 || EPI == 3 || EPI == 4) bv = bias[col];
      #pragma unroll
      for (int r = 0; r < 4; ++r) {
        const size_t idx = (size_t)blockIdx.z * cstr + (size_t)(r0 + r) * ldc + col;
        const float v = acc[mi][ni][r];
        if      (EPI == 0) Ch[idx] = f2bf(v + bv);
        else if (EPI == 1) Cf[idx] = v * scale;
        else if (EPI == 3) Ch[idx] = f2bf(fmaxf(v + bv, 0.f));
        else if (EPI == 4) Cf[idx] = v + bv + add[idx];
      }
    }
  }
}

// ---------------------------------------------------------------------------
// Deep-pipelined 256x128 NT GEMM (round-2 proven).
// EPI: 0 col-bias->bf16 | 1 *scale->f32 | 2 +add->f32 | 4 col-bias,+add->f32
//      5 row-bias->bf16 (for direct V^T projection)
// ---------------------------------------------------------------------------
template<int EPI>
__global__ __launch_bounds__(512, 2) void gemm8p(
    const u16* __restrict__ A, int lda, long long astr,
    const u16* __restrict__ B, int ldb, long long bstr,
    void* __restrict__ C, int ldc, long long cstr,
    const float* __restrict__ bias,
    const float* __restrict__ add,
    float scale, int Kdim)
{
  __shared__ i32x4 lds4[9216];           // 3 slots x 48KB (A 32KB + B 16KB)
  const int SLOT = 49152;

  const int tid  = threadIdx.x;
  const int lane = tid & 63;
  const int w    = tid >> 6;
  const int wr   = w >> 1, wc = w & 1;
  const int l15  = lane & 15, l4 = lane >> 4;

  const int gx   = gridDim.x;
  const int nwg  = gx * gridDim.y;
  const int orig = blockIdx.y * gx + blockIdx.x;
  const int t    = ((nwg & 7) == 0) ? ((orig & 7) * (nwg >> 3) + (orig >> 3)) : orig;
  const int bx   = t % gx, by = t / gx;

  const u16* Ab = A + (size_t)blockIdx.z * astr + (size_t)by * 256 * lda;
  const u16* Bb = B + (size_t)blockIdx.z * bstr + (size_t)bx * 128 * ldb;

  size_t gaoff[4], gboff[2];
  #pragma unroll
  for (int i = 0; i < 4; ++i) {
    const int idx = i * 512 + tid, row = idx >> 3, gc = (idx & 7) ^ (row & 7);
    gaoff[i] = (size_t)row * lda + gc * 8;
  }
  #pragma unroll
  for (int j = 0; j < 2; ++j) {
    const int idx = j * 512 + tid, row = idx >> 3, gc = (idx & 7) ^ (row & 7);
    gboff[j] = (size_t)row * ldb + gc * 8;
  }

  int aoff[4], boff[4], cp16[2];
  #pragma unroll
  for (int m = 0; m < 4; ++m) aoff[m] = (wr * 64 + m * 16 + l15) * 128;
  #pragma unroll
  for (int n = 0; n < 4; ++n) boff[n] = 32768 + (wc * 64 + n * 16 + l15) * 128;
  cp16[0] = ((0 + l4) ^ (l15 & 7)) * 16;
  cp16[1] = ((4 + l4) ^ (l15 & 7)) * 16;

  f32x4 acc[4][4] = {};
  const int NT = Kdim >> 6;
  char* lbase = (char*)lds4;

  {
    char* s0 = lbase;
    char* s1 = lbase + SLOT;
    #pragma unroll
    for (int i = 0; i < 4; ++i) gld16(Ab + gaoff[i],      s0 + (i * 512 + w * 64) * 16);
    #pragma unroll
    for (int j = 0; j < 2; ++j) gld16(Bb + gboff[j],      s0 + 32768 + (j * 512 + w * 64) * 16);
    #pragma unroll
    for (int i = 0; i < 4; ++i) gld16(Ab + gaoff[i] + 64, s1 + (i * 512 + w * 64) * 16);
    #pragma unroll
    for (int j = 0; j < 2; ++j) gld16(Bb + gboff[j] + 64, s1 + 32768 + (j * 512 + w * 64) * 16);
  }

  int s = 0;
  for (int T = 0; T < NT; ++T) {
    const bool st  = (T + 2 < NT);
    const size_t kk = (size_t)(T + 2) * 64;
    const char* rA = lbase + s * SLOT;
    char* wS = lbase + ((s + 2 >= 3) ? (s - 1) : (s + 2)) * SLOT;

    if (T == NT - 1) VMW(0);
    else             VMW(6);
    BARR();
    SCHED0();

    bf16x8 b0, b1, b2, b3, a0, a1;

    b0 = RD16(rA + boff[0] + cp16[0]);
    b1 = RD16(rA + boff[1] + cp16[0]);
    b2 = RD16(rA + boff[2] + cp16[0]);
    b3 = RD16(rA + boff[3] + cp16[0]);
    a0 = RD16(rA + aoff[0] + cp16[0]);
    a1 = RD16(rA + aoff[1] + cp16[0]);
    if (st) {
      gld16(Ab + gaoff[0] + kk, wS + (0 * 512 + w * 64) * 16);
      gld16(Ab + gaoff[1] + kk, wS + (1 * 512 + w * 64) * 16);
    }
    BARR();
    LGKM(0);
    SCHED0();
    __builtin_amdgcn_s_setprio(1);
    acc[0][0] = MFMA16(a0, b0, acc[0][0]);
    acc[0][1] = MFMA16(a0, b1, acc[0][1]);
    acc[0][2] = MFMA16(a0, b2, acc[0][2]);
    acc[0][3] = MFMA16(a0, b3, acc[0][3]);
    acc[1][0] = MFMA16(a1, b0, acc[1][0]);
    acc[1][1] = MFMA16(a1, b1, acc[1][1]);
    acc[1][2] = MFMA16(a1, b2, acc[1][2]);
    acc[1][3] = MFMA16(a1, b3, acc[1][3]);
    __builtin_amdgcn_s_setprio(0);

    a0 = RD16(rA + aoff[2] + cp16[0]);
    a1 = RD16(rA + aoff[3] + cp16[0]);
    if (st) {
      gld16(Ab + gaoff[2] + kk, wS + (2 * 512 + w * 64) * 16);
      gld16(Ab + gaoff[3] + kk, wS + (3 * 512 + w * 64) * 16);
    }
    BARR();
    LGKM(0);
    SCHED0();
    __builtin_amdgcn_s_setprio(1);
    acc[2][0] = MFMA16(a0, b0, acc[2][0]);
    acc[2][1] = MFMA16(a0, b1, acc[2][1]);
    acc[2][2] = MFMA16(a0, b2, acc[2][2]);
    acc[2][3] = MFMA16(a0, b3, acc[2][3]);
    acc[3][0] = MFMA16(a1, b0, acc[3][0]);
    acc[3][1] = MFMA16(a1, b1, acc[3][1]);
    acc[3][2] = MFMA16(a1, b2, acc[3][2]);
    acc[3][3] = MFMA16(a1, b3, acc[3][3]);
    __builtin_amdgcn_s_setprio(0);

    b0 = RD16(rA + boff[0] + cp16[1]);
    b1 = RD16(rA + boff[1] + cp16[1]);
    b2 = RD16(rA + boff[2] + cp16[1]);
    b3 = RD16(rA + boff[3] + cp16[1]);
    a0 = RD16(rA + aoff[0] + cp16[1]);
    a1 = RD16(rA + aoff[1] + cp16[1]);
    if (st) {
      gld16(Bb + gboff[0] + kk, wS + 32768 + (0 * 512 + w * 64) * 16);
    }
    BARR();
    LGKM(0);
    SCHED0();
    __builtin_amdgcn_s_setprio(1);
    acc[0][0] = MFMA16(a0, b0, acc[0][0]);
    acc[0][1] = MFMA16(a0, b1, acc[0][1]);
    acc[0][2] = MFMA16(a0, b2, acc[0][2]);
    acc[0][3] = MFMA16(a0, b3, acc[0][3]);
    acc[1][0] = MFMA16(a1, b0, acc[1][0]);
    acc[1][1] = MFMA16(a1, b1, acc[1][1]);
    acc[1][2] = MFMA16(a1, b2, acc[1][2]);
    acc[1][3] = MFMA16(a1, b3, acc[1][3]);
    __builtin_amdgcn_s_setprio(0);

    a0 = RD16(rA + aoff[2] + cp16[1]);
    a1 = RD16(rA + aoff[3] + cp16[1]);
    if (st) {
      gld16(Bb + gboff[1] + kk, wS + 32768 + (1 * 512 + w * 64) * 16);
    }
    BARR();
    LGKM(0);
    SCHED0();
    __builtin_amdgcn_s_setprio(1);
    acc[2][0] = MFMA16(a0, b0, acc[2][0]);
    acc[2][1] = MFMA16(a0, b1, acc[2][1]);
    acc[2][2] = MFMA16(a0, b2, acc[2][2]);
    acc[2][3] = MFMA16(a0, b3, acc[2][3]);
    acc[3][0] = MFMA16(a1, b0, acc[3][0]);
    acc[3][1] = MFMA16(a1, b1, acc[3][1]);
    acc[3][2] = MFMA16(a1, b2, acc[3][2]);
    acc[3][3] = MFMA16(a1, b3, acc[3][3]);
    __builtin_amdgcn_s_setprio(0);

    s = (s + 1 == 3) ? 0 : s + 1;
  }

  const int bm0 = by * 256 + wr * 64;
  const int bn0 = bx * 128 + wc * 64;
  float* Cf = (float*)C;
  u16*   Ch = (u16*)C;
  #pragma unroll
  for (int mi = 0; mi < 4; ++mi) {
    #pragma unroll
    for (int ni = 0; ni < 4; ++ni) {
      const int col = bn0 + ni * 16 + l15;
      const int r0  = bm0 + mi * 16 + l4 * 4;
      float bv = 0.f;
      if (EPI == 0 || EPI == 4) bv = bias[col];
      #pragma unroll
      for (int r = 0; r < 4; ++r) {
        const size_t idx = (size_t)blockIdx.z * cstr + (size_t)(r0 + r) * ldc + col;
        const float v = acc[mi][ni][r];
        if      (EPI == 0) Ch[idx] = f2bf(v + bv);
        else if (EPI == 1) Cf[idx] = v * scale;
        else if (EPI == 2) Cf[idx] = v + add[idx];
        else if (EPI == 4) Cf[idx] = v + bv + add[idx];
        else if (EPI == 5) Ch[idx] = f2bf(v + bias[r0 + r]);
      }
    }
  }
}

// ---------------------------------------------------------------------------
__global__ __launch_bounds__(256) void ln_kernel(
    const float* __restrict__ x, const float* __restrict__ g,
    const float* __restrict__ be, u16* __restrict__ out)
{
  const int row = blockIdx.x;
  const int tid = threadIdx.x;
  const float4 v = ((const float4*)(x + (size_t)row * EMBED))[tid];
  float s  = v.x + v.y + v.z + v.w;
  float s2 = v.x * v.x + v.y * v.y + v.z * v.z + v.w * v.w;
  #pragma unroll
  for (int m = 1; m < 64; m <<= 1) { s += __shfl_xor(s, m); s2 += __shfl_xor(s2, m); }
  __shared__ float ls[4], ls2[4];
  const int w = tid >> 6;
  if ((tid & 63) == 0) { ls[w] = s; ls2[w] = s2; }
  __syncthreads();
  s  = ls[0] + ls[1] + ls[2] + ls[3];
  s2 = ls2[0] + ls2[1] + ls2[2] + ls2[3];
  const float mu   = s * (1.f / EMBED);
  const float var  = s2 * (1.f / EMBED) - mu * mu;
  const float rstd = rsqrtf(var + 1e-5f);
  const float4 gv = ((const float4*)g)[tid];
  const float4 bv = ((const float4*)be)[tid];
  ushort4 o;
  o.x = f2bf((v.x - mu) * rstd * gv.x + bv.x);
  o.y = f2bf((v.y - mu) * rstd * gv.y + bv.y);
  o.z = f2bf((v.z - mu) * rstd * gv.z + bv.z);
  o.w = f2bf((v.w - mu) * rstd * gv.w + bv.w);
  ((ushort4*)(out + (size_t)row * EMBED))[tid] = o;
}

// ---------------------------------------------------------------------------
__global__ __launch_bounds__(256) void softmax_kernel(
    const float* __restrict__ S, u16* __restrict__ P)
{
  const int tid = threadIdx.x;
  const size_t base = ((size_t)blockIdx.y * SEQ + blockIdx.x) * SEQ;
  const float4* src = (const float4*)(S + base);
  float4 a = src[tid];
  float4 b = src[tid + 256];
  float m = fmaxf(fmaxf(fmaxf(a.x, a.y), fmaxf(a.z, a.w)),
                  fmaxf(fmaxf(b.x, b.y), fmaxf(b.z, b.w)));
  #pragma unroll
  for (int msk = 1; msk < 64; msk <<= 1) m = fmaxf(m, __shfl_xor(m, msk));
  __shared__ float red[8];
  const int w = tid >> 6;
  if ((tid & 63) == 0) red[w] = m;
  __syncthreads();
  m = fmaxf(fmaxf(red[0], red[1]), fmaxf(red[2], red[3]));
  a.x = __expf(a.x - m); a.y = __expf(a.y - m); a.z = __expf(a.z - m); a.w = __expf(a.w - m);
  b.x = __expf(b.x - m); b.y = __expf(b.y - m); b.z = __expf(b.z - m); b.w = __expf(b.w - m);
  float s = a.x + a.y + a.z + a.w + b.x + b.y + b.z + b.w;
  #pragma unroll
  for (int msk = 1; msk < 64; msk <<= 1) s += __shfl_xor(s, msk);
  if ((tid & 63) == 0) red[4 + w] = s;
  __syncthreads();
  s = red[4] + red[5] + red[6] + red[7];
  const float inv = 1.0f / s;
  ushort4 oa, ob;
  oa.x = f2bf(a.x * inv); oa.y = f2bf(a.y * inv); oa.z = f2bf(a.z * inv); oa.w = f2bf(a.w * inv);
  ob.x = f2bf(b.x * inv); ob.y = f2bf(b.y * inv); ob.z = f2bf(b.z * inv); ob.w = f2bf(b.w * inv);
  ushort4* dst = (ushort4*)(P + base);
  dst[tid]       = oa;
  dst[tid + 256] = ob;
}

// ---------------------------------------------------------------------------
__global__ void transpose_cast_f32(const float* __restrict__ W, u16* __restrict__ Wt,
                                   int K, int N)
{
  __shared__ float t[32][33];
  const int tx = threadIdx.x, ty = threadIdx.y;
  const int n0 = blockIdx.x * 32, k0 = blockIdx.y * 32;
  #pragma unroll
  for (int i = 0; i < 4; ++i)
    t[ty + i * 8][tx] = W[(size_t)(k0 + ty + i * 8) * N + n0 + tx];
  __syncthreads();
  #pragma unroll
  for (int i = 0; i < 4; ++i)
    Wt[(size_t)(n0 + ty + i * 8) * K + k0 + tx] = f2bf(t[tx][ty + i * 8]);
}

__global__ void concat_bias2(const float* __restrict__ a, const float* __restrict__ b,
                             float* __restrict__ o)
{
  const int i = blockIdx.x * 1024 + threadIdx.x;
  o[i] = (i < 1024) ? a[i] : b[i - 1024];
}

// ---------------------------------------------------------------------------
extern "C" void kernel_launch(void* const* d_in, const int* in_sizes, int n_in,
                              void* d_out, int out_size, void* d_ws, size_t ws_size,
                              hipStream_t stream)
{
  const float* x   = (const float*)d_in[0];
  const float* Wq  = (const float*)d_in[1];
  const float* bq  = (const float*)d_in[2];
  const float* Wk  = (const float*)d_in[3];
  const float* bk  = (const float*)d_in[4];
  const float* Wv  = (const float*)d_in[5];
  const float* bv  = (const float*)d_in[6];
  const float* W1  = (const float*)d_in[7];
  const float* b1  = (const float*)d_in[8];
  const float* W2  = (const float*)d_in[9];
  const float* b2  = (const float*)d_in[10];
  const float* g1  = (const float*)d_in[11];
  const float* be1 = (const float*)d_in[12];
  const float* g2  = (const float*)d_in[13];
  const float* be2 = (const float*)d_in[14];
  float* out = (float*)d_out;

  const size_t RD = (size_t)NB * SEQ * EMBED;

  char* base = (char*)d_ws;
  size_t o = 0;
  auto alloc = [&](size_t bytes) -> void* {
    o = (o + 255) & ~(size_t)255;
    void* p = base + o;
    o += bytes;
    return p;
  };

  u16*   wqkT = (u16*)alloc((size_t)2 * EMBED * EMBED * 2);   // [2048][1024]
  u16*   wvT  = (u16*)alloc((size_t)EMBED * EMBED * 2);       // [1024][1024]
  u16*   w1T  = (u16*)alloc((size_t)HID * EMBED * 2);         // [4096][1024]
  u16*   w2T  = (u16*)alloc((size_t)EMBED * HID * 2);         // [1024][4096]
  float* bqk  = (float*)alloc(2048 * 4);
  u16*   h    = (u16*)alloc(RD * 2);
  u16*   QKb  = (u16*)alloc(RD * 2 * 2);                      // [8192][2048]
  u16*   Vt   = (u16*)alloc(RD * 2);                          // [4][1024][2048]
  float* x2   = (float*)alloc(RD * 4);

  const size_t need_batched = o + (size_t)NB * SEQ * SEQ * 6 + 1024;
  const int NZ = (ws_size >= need_batched) ? NB : 1;
  float* Sbuf = (float*)alloc((size_t)NZ * SEQ * SEQ * 4);
  u16*   Pb   = (u16*)alloc((size_t)NZ * SEQ * SEQ * 2);
  u16*   ff   = (NZ == NB) ? (u16*)Sbuf                       // 67MB alias
                           : (u16*)alloc((size_t)NB * SEQ * HID * 2);

  const dim3 blk(512);
  const dim3 tblk(32, 8);

  // weights -> bf16 [N][K]
  transpose_cast_f32<<<dim3(32, 32), tblk, 0, stream>>>(Wq, wqkT, EMBED, EMBED);
  transpose_cast_f32<<<dim3(32, 32), tblk, 0, stream>>>(Wk, wqkT + (size_t)EMBED * EMBED, EMBED, EMBED);
  transpose_cast_f32<<<dim3(32, 32), tblk, 0, stream>>>(Wv, wvT, EMBED, EMBED);
  transpose_cast_f32<<<dim3(HID / 32, EMBED / 32), tblk, 0, stream>>>(W1, w1T, EMBED, HID);
  transpose_cast_f32<<<dim3(EMBED / 32, HID / 32), tblk, 0, stream>>>(W2, w2T, HID, EMBED);
  concat_bias2<<<dim3(2), dim3(1024), 0, stream>>>(bq, bk, bqk);

  // LN1
  ln_kernel<<<dim3(NB * SEQ), dim3(256), 0, stream>>>(x, g1, be1, h);

  // QK projection: [8192][2048]  (512 blocks = 2 exact CU-waves)
  gemm8p<0><<<dim3(2048 / 128, NB * SEQ / 256, 1), blk, 0, stream>>>(
      h, EMBED, 0LL, wqkT, EMBED, 0LL, QKb, 2048, 0LL, bqk, nullptr, 1.f, EMBED);

  // V^T projection (direct, no transpose): Vt[b][d][s] = sum_k WvT[d][k]*h[b,s,k] + bv[d]
  gemm8p<5><<<dim3(SEQ / 128, EMBED / 256, NB), blk, 0, stream>>>(
      wvT, EMBED, 0LL, h, EMBED, (long long)SEQ * EMBED,
      Vt, SEQ, (long long)EMBED * SEQ, bv, nullptr, 1.f, EMBED);

  // attention
  for (int b = 0; b < NB; b += NZ) {
    const u16* Qp  = QKb + (size_t)b * SEQ * 2048;
    const u16* Kp  = Qp + 1024;
    const u16* Vtp = Vt + (size_t)b * EMBED * SEQ;
    float* x2p     = x2 + (size_t)b * SEQ * EMBED;
    const float* xp = x + (size_t)b * SEQ * EMBED;
    gemm8p<1><<<dim3(SEQ / 128, SEQ / 256, NZ), blk, 0, stream>>>(
        Qp, 2048, (long long)SEQ * 2048, Kp, 2048, (long long)SEQ * 2048,
        Sbuf, SEQ, (long long)SEQ * SEQ, nullptr, nullptr, 0.03125f, EMBED);
    softmax_kernel<<<dim3(SEQ, NZ), dim3(256), 0, stream>>>(Sbuf, Pb);
    gemm8p<2><<<dim3(EMBED / 128, SEQ / 256, NZ), blk, 0, stream>>>(
        Pb, SEQ, (long long)SEQ * SEQ, Vtp, SEQ, (long long)EMBED * SEQ,
        x2p, EMBED, (long long)SEQ * EMBED, nullptr, xp, 1.f, SEQ);
  }

  // LN2
  ln_kernel<<<dim3(NB * SEQ), dim3(256), 0, stream>>>(x2, g2, be2, h);

  // MLP
  gemm256<3><<<dim3(HID / 256, NB * SEQ / 256, 1), blk, 0, stream>>>(
      h, EMBED, 0LL, w1T, EMBED, 0LL, ff, HID, 0LL, b1, nullptr, 1.f, EMBED);
  gemm8p<4><<<dim3(EMBED / 128, NB * SEQ / 256, 1), blk, 0, stream>>>(
      ff, HID, 0LL, w2T, HID, 0LL, out, EMBED, 0LL, b2, x2, 1.f, HID);
}